// Round 4
// baseline (304.670 us; speedup 1.0000x reference)
//
#include <hip/hip_runtime.h>
#include <hip/hip_bf16.h>

#define C 64

// ---- count in-degree over dst; atomic return = rank of edge within its bucket ----
__global__ void count_deg_kernel(const int* __restrict__ dst, unsigned* __restrict__ deg,
                                 unsigned* __restrict__ rank, int E) {
    int e = blockIdx.x * blockDim.x + threadIdx.x;
    if (e < E) {
        rank[e] = atomicAdd(&deg[dst[e]], 1u);
    }
}

// ---- exclusive scan level 1 (1024/block) + dis = rsqrt(deg+1) fused ----
__global__ void scan1_kernel(const unsigned* __restrict__ deg, unsigned* __restrict__ offs,
                             unsigned* __restrict__ bsum, float* __restrict__ dis, int n) {
    __shared__ unsigned s[256];
    int t = threadIdx.x;
    int base = blockIdx.x * 1024 + t * 4;
    unsigned v0 = 0, v1 = 0, v2 = 0, v3 = 0;
    if (base + 0 < n) v0 = deg[base + 0];
    if (base + 1 < n) v1 = deg[base + 1];
    if (base + 2 < n) v2 = deg[base + 2];
    if (base + 3 < n) v3 = deg[base + 3];
    if (base + 0 < n) dis[base + 0] = rsqrtf((float)(v0 + 1u));
    if (base + 1 < n) dis[base + 1] = rsqrtf((float)(v1 + 1u));
    if (base + 2 < n) dis[base + 2] = rsqrtf((float)(v2 + 1u));
    if (base + 3 < n) dis[base + 3] = rsqrtf((float)(v3 + 1u));
    s[t] = v0 + v1 + v2 + v3;
    __syncthreads();
    for (int d = 1; d < 256; d <<= 1) {
        unsigned val = (t >= d) ? s[t - d] : 0u;
        __syncthreads();
        s[t] += val;
        __syncthreads();
    }
    unsigned excl = (t == 0) ? 0u : s[t - 1];
    if (t == 255) bsum[blockIdx.x] = s[255];
    if (base + 0 < n) offs[base + 0] = excl;
    if (base + 1 < n) offs[base + 1] = excl + v0;
    if (base + 2 < n) offs[base + 2] = excl + v0 + v1;
    if (base + 3 < n) offs[base + 3] = excl + v0 + v1 + v2;
}

// ---- scan block sums (single block; nb <= 256) ----
__global__ void scan2_kernel(unsigned* __restrict__ bsum, int nb) {
    __shared__ unsigned s[256];
    int t = threadIdx.x;
    s[t] = (t < nb) ? bsum[t] : 0u;
    __syncthreads();
    for (int d = 1; d < 256; d <<= 1) {
        unsigned val = (t >= d) ? s[t - d] : 0u;
        __syncthreads();
        s[t] += val;
        __syncthreads();
    }
    if (t < nb) bsum[t] = (t == 0) ? 0u : s[t - 1];
}

// ---- bucket edges by dst using precomputed rank (no atomics) ----
__global__ void bucket_kernel(const int* __restrict__ src, const int* __restrict__ dst,
                              const unsigned* __restrict__ offs, const unsigned* __restrict__ bsum,
                              const unsigned* __restrict__ rank, unsigned* __restrict__ ssrc, int E) {
    int e = blockIdx.x * blockDim.x + threadIdx.x;
    if (e < E) {
        int d = dst[e];
        unsigned pos = offs[d] + bsum[d >> 10] + rank[e];
        ssrc[pos] = (unsigned)src[e];
    }
}

// ---- hs = dis[row] * (x @ W): W column held in VGPRs, x rows via scalar loads ----
__global__ void gemm64_kernel(const float* __restrict__ x, const float* __restrict__ W,
                              const float* __restrict__ dis, float* __restrict__ hs, int n) {
    __shared__ float Wl[64 * 64];
    int tid = threadIdx.x;
    for (int i = tid; i < 1024; i += 256) {
        ((float4*)Wl)[i] = ((const float4*)W)[i];
    }
    __syncthreads();
    int c = tid & 63;
    // W column c -> 64 VGPRs (conflict-free LDS reads, once per block)
    float wcol[64];
    #pragma unroll
    for (int k = 0; k < 64; ++k) {
        wcol[k] = Wl[k * 64 + c];
    }
    // wave-uniform row base so x-row loads become scalar (s_load) broadcasts
    int wv = __builtin_amdgcn_readfirstlane((int)(threadIdx.x >> 6));
    int rbase = blockIdx.x * 64 + wv * 16;
    for (int j = 0; j < 16; ++j) {
        int row = rbase + j;
        if (row >= n) break;   // wave-uniform branch
        const float* xr = x + (size_t)row * C;
        float acc = 0.0f;
        #pragma unroll
        for (int k = 0; k < 64; ++k) {
            acc += xr[k] * wcol[k];
        }
        hs[(size_t)row * C + c] = acc * dis[row];
    }
}

// ---- gather: one wave per node; 8 edges in flight (16 lanes x float4 each) ----
__global__ void gather_kernel(const unsigned* __restrict__ offs, const unsigned* __restrict__ bsum,
                              const unsigned* __restrict__ deg, const unsigned* __restrict__ ssrc,
                              const float* __restrict__ dis, const float* __restrict__ hs,
                              const float* __restrict__ b, float* __restrict__ out, int n) {
    int node = blockIdx.x * 4 + (threadIdx.x >> 6);
    if (node >= n) return;
    int lane = threadIdx.x & 63;
    int g = lane >> 4;          // edge group 0..3
    int l = lane & 15;          // float4 slot within row
    unsigned off = offs[node] + bsum[node >> 10];
    unsigned dg  = deg[node];
    float4 acc = {0.f, 0.f, 0.f, 0.f};
    unsigned k = 0;
    for (; k + 8 <= dg; k += 8) {
        unsigned s0 = ssrc[off + k + g];
        unsigned s1 = ssrc[off + k + 4 + g];
        float4 v0 = ((const float4*)(hs + (size_t)s0 * C))[l];
        float4 v1 = ((const float4*)(hs + (size_t)s1 * C))[l];
        acc.x += v0.x + v1.x; acc.y += v0.y + v1.y;
        acc.z += v0.z + v1.z; acc.w += v0.w + v1.w;
    }
    if (k + 4 <= dg) {
        unsigned s0 = ssrc[off + k + g];
        float4 v0 = ((const float4*)(hs + (size_t)s0 * C))[l];
        acc.x += v0.x; acc.y += v0.y; acc.z += v0.z; acc.w += v0.w;
        k += 4;
    }
    if (k + g < dg) {
        unsigned s0 = ssrc[off + k + g];
        float4 v0 = ((const float4*)(hs + (size_t)s0 * C))[l];
        acc.x += v0.x; acc.y += v0.y; acc.z += v0.z; acc.w += v0.w;
    }
    acc.x += __shfl_xor(acc.x, 16); acc.y += __shfl_xor(acc.y, 16);
    acc.z += __shfl_xor(acc.z, 16); acc.w += __shfl_xor(acc.w, 16);
    acc.x += __shfl_xor(acc.x, 32); acc.y += __shfl_xor(acc.y, 32);
    acc.z += __shfl_xor(acc.z, 32); acc.w += __shfl_xor(acc.w, 32);
    if (g == 0) {
        float di = dis[node];
        float4 hv = ((const float4*)(hs + (size_t)node * C))[l];
        float4 bv = ((const float4*)b)[l];
        float4 o;
        o.x = di * (hv.x + acc.x) + bv.x;
        o.y = di * (hv.y + acc.y) + bv.y;
        o.z = di * (hv.z + acc.z) + bv.z;
        o.w = di * (hv.w + acc.w) + bv.w;
        ((float4*)(out + (size_t)node * C))[l] = o;
    }
}

extern "C" void kernel_launch(void* const* d_in, const int* in_sizes, int n_in,
                              void* d_out, int out_size, void* d_ws, size_t ws_size,
                              hipStream_t stream) {
    const float* x   = (const float*)d_in[0];
    const int*   ei  = (const int*)d_in[1];   // [2, E]: src = ei[e], dst = ei[E+e]
    const float* W   = (const float*)d_in[2];
    const float* b   = (const float*)d_in[3];
    float*       out = (float*)d_out;

    const int N = in_sizes[0] / C;
    const int E = in_sizes[1] / 2;
    const int* src = ei;
    const int* dst = ei + E;

    // workspace layout (256B aligned slots)
    char* ws = (char*)d_ws;
    size_t o = 0;
    auto carve = [&](size_t bytes) { char* p = ws + o; o = (o + bytes + 255) & ~(size_t)255; return p; };
    unsigned* deg    = (unsigned*)carve((size_t)N * 4);
    unsigned* offs   = (unsigned*)carve((size_t)N * 4);
    unsigned* bsum   = (unsigned*)carve(1024 * 4);
    float*    dis    = (float*)carve((size_t)N * 4);
    unsigned* rank   = (unsigned*)carve((size_t)E * 4);
    unsigned* ssrc   = (unsigned*)carve((size_t)E * 4);
    float*    hs     = (float*)carve((size_t)N * C * 4);

    // zero degree counters only
    hipMemsetAsync(deg, 0, (size_t)N * 4, stream);

    // degree histogram + per-edge rank
    count_deg_kernel<<<(E + 255) / 256, 256, 0, stream>>>(dst, deg, rank, E);

    // exclusive prefix sum of deg -> offs (+ fused dis)
    int nb = (N + 1023) / 1024;
    scan1_kernel<<<nb, 256, 0, stream>>>(deg, offs, bsum, dis, N);
    scan2_kernel<<<1, 256, 0, stream>>>(bsum, nb);

    // counting-sort edges by dst (atomic-free)
    bucket_kernel<<<(E + 255) / 256, 256, 0, stream>>>(src, dst, offs, bsum, rank, ssrc, E);

    // hs = dis * (x @ W)
    gemm64_kernel<<<(N + 63) / 64, 256, 0, stream>>>(x, W, dis, hs, N);

    // gather + self loop + bias
    gather_kernel<<<(N + 3) / 4, 256, 0, stream>>>(offs, bsum, deg, ssrc, dis, hs, b, out, N);
}

// Round 5
// 303.781 us; speedup vs baseline: 1.0029x; 1.0029x over previous
//
#include <hip/hip_runtime.h>
#include <hip/hip_bf16.h>

#define C 64

// ---- count in-degree over dst; atomic return = rank of edge within its bucket ----
__global__ void count_deg_kernel(const int* __restrict__ dst, unsigned* __restrict__ deg,
                                 unsigned* __restrict__ rank, int E) {
    int e = blockIdx.x * blockDim.x + threadIdx.x;
    if (e < E) {
        rank[e] = atomicAdd(&deg[dst[e]], 1u);
    }
}

// ---- exclusive scan level 1 (1024/block) + dis = rsqrt(deg+1) fused ----
__global__ void scan1_kernel(const unsigned* __restrict__ deg, unsigned* __restrict__ offs,
                             unsigned* __restrict__ bsum, float* __restrict__ dis, int n) {
    __shared__ unsigned s[256];
    int t = threadIdx.x;
    int base = blockIdx.x * 1024 + t * 4;
    unsigned v0 = 0, v1 = 0, v2 = 0, v3 = 0;
    if (base + 0 < n) v0 = deg[base + 0];
    if (base + 1 < n) v1 = deg[base + 1];
    if (base + 2 < n) v2 = deg[base + 2];
    if (base + 3 < n) v3 = deg[base + 3];
    if (base + 0 < n) dis[base + 0] = rsqrtf((float)(v0 + 1u));
    if (base + 1 < n) dis[base + 1] = rsqrtf((float)(v1 + 1u));
    if (base + 2 < n) dis[base + 2] = rsqrtf((float)(v2 + 1u));
    if (base + 3 < n) dis[base + 3] = rsqrtf((float)(v3 + 1u));
    s[t] = v0 + v1 + v2 + v3;
    __syncthreads();
    for (int d = 1; d < 256; d <<= 1) {
        unsigned val = (t >= d) ? s[t - d] : 0u;
        __syncthreads();
        s[t] += val;
        __syncthreads();
    }
    unsigned excl = (t == 0) ? 0u : s[t - 1];
    if (t == 255) bsum[blockIdx.x] = s[255];
    if (base + 0 < n) offs[base + 0] = excl;
    if (base + 1 < n) offs[base + 1] = excl + v0;
    if (base + 2 < n) offs[base + 2] = excl + v0 + v1;
    if (base + 3 < n) offs[base + 3] = excl + v0 + v1 + v2;
}

// ---- scan block sums (single block; nb <= 256) ----
__global__ void scan2_kernel(unsigned* __restrict__ bsum, int nb) {
    __shared__ unsigned s[256];
    int t = threadIdx.x;
    s[t] = (t < nb) ? bsum[t] : 0u;
    __syncthreads();
    for (int d = 1; d < 256; d <<= 1) {
        unsigned val = (t >= d) ? s[t - d] : 0u;
        __syncthreads();
        s[t] += val;
        __syncthreads();
    }
    if (t < nb) bsum[t] = (t == 0) ? 0u : s[t - 1];
}

// ---- bucket edges by dst using precomputed rank (no atomics) ----
__global__ void bucket_kernel(const int* __restrict__ src, const int* __restrict__ dst,
                              const unsigned* __restrict__ offs, const unsigned* __restrict__ bsum,
                              const unsigned* __restrict__ rank, unsigned* __restrict__ ssrc, int E) {
    int e = blockIdx.x * blockDim.x + threadIdx.x;
    if (e < E) {
        int d = dst[e];
        unsigned pos = offs[d] + bsum[d >> 10] + rank[e];
        ssrc[pos] = (unsigned)src[e];
    }
}

// ---- hs = dis[row] * (x @ W): W column in VGPRs, x rows via s_load broadcasts ----
// __launch_bounds__(256,4): 128-VGPR cap so wcol[64] stays in registers (round-4
// default 64-cap spilled it to scratch: 292MB fetch).
__global__ void __launch_bounds__(256, 4)
gemm64_kernel(const float* __restrict__ x, const float* __restrict__ W,
              const float* __restrict__ dis, float* __restrict__ hs, int n) {
    __shared__ float Wl[64 * 64];
    int tid = threadIdx.x;
    for (int i = tid; i < 1024; i += 256) {
        ((float4*)Wl)[i] = ((const float4*)W)[i];
    }
    __syncthreads();
    int c = tid & 63;
    // W column c -> 64 VGPRs (conflict-free LDS reads, once per block)
    float wcol[64];
    #pragma unroll
    for (int k = 0; k < 64; ++k) {
        wcol[k] = Wl[k * 64 + c];
    }
    // wave-uniform row base so x-row loads become scalar (s_load) broadcasts
    int wv = __builtin_amdgcn_readfirstlane((int)(threadIdx.x >> 6));
    int rbase = blockIdx.x * 64 + wv * 16;
    for (int j = 0; j < 16; ++j) {
        int row = rbase + j;
        if (row >= n) break;   // wave-uniform branch
        const float* xr = x + (size_t)row * C;
        float acc = 0.0f;
        #pragma unroll
        for (int k = 0; k < 64; ++k) {
            acc += xr[k] * wcol[k];
        }
        hs[(size_t)row * C + c] = acc * dis[row];
    }
}

// ---- gather: one wave per node; 8 edges in flight (16 lanes x float4 each) ----
__global__ void gather_kernel(const unsigned* __restrict__ offs, const unsigned* __restrict__ bsum,
                              const unsigned* __restrict__ deg, const unsigned* __restrict__ ssrc,
                              const float* __restrict__ dis, const float* __restrict__ hs,
                              const float* __restrict__ b, float* __restrict__ out, int n) {
    int node = blockIdx.x * 4 + (threadIdx.x >> 6);
    if (node >= n) return;
    int lane = threadIdx.x & 63;
    int g = lane >> 4;          // edge group 0..3
    int l = lane & 15;          // float4 slot within row
    unsigned off = offs[node] + bsum[node >> 10];
    unsigned dg  = deg[node];
    float4 acc = {0.f, 0.f, 0.f, 0.f};
    unsigned k = 0;
    for (; k + 8 <= dg; k += 8) {
        unsigned s0 = ssrc[off + k + g];
        unsigned s1 = ssrc[off + k + 4 + g];
        float4 v0 = ((const float4*)(hs + (size_t)s0 * C))[l];
        float4 v1 = ((const float4*)(hs + (size_t)s1 * C))[l];
        acc.x += v0.x + v1.x; acc.y += v0.y + v1.y;
        acc.z += v0.z + v1.z; acc.w += v0.w + v1.w;
    }
    if (k + 4 <= dg) {
        unsigned s0 = ssrc[off + k + g];
        float4 v0 = ((const float4*)(hs + (size_t)s0 * C))[l];
        acc.x += v0.x; acc.y += v0.y; acc.z += v0.z; acc.w += v0.w;
        k += 4;
    }
    if (k + g < dg) {
        unsigned s0 = ssrc[off + k + g];
        float4 v0 = ((const float4*)(hs + (size_t)s0 * C))[l];
        acc.x += v0.x; acc.y += v0.y; acc.z += v0.z; acc.w += v0.w;
    }
    acc.x += __shfl_xor(acc.x, 16); acc.y += __shfl_xor(acc.y, 16);
    acc.z += __shfl_xor(acc.z, 16); acc.w += __shfl_xor(acc.w, 16);
    acc.x += __shfl_xor(acc.x, 32); acc.y += __shfl_xor(acc.y, 32);
    acc.z += __shfl_xor(acc.z, 32); acc.w += __shfl_xor(acc.w, 32);
    if (g == 0) {
        float di = dis[node];
        float4 hv = ((const float4*)(hs + (size_t)node * C))[l];
        float4 bv = ((const float4*)b)[l];
        float4 o;
        o.x = di * (hv.x + acc.x) + bv.x;
        o.y = di * (hv.y + acc.y) + bv.y;
        o.z = di * (hv.z + acc.z) + bv.z;
        o.w = di * (hv.w + acc.w) + bv.w;
        ((float4*)(out + (size_t)node * C))[l] = o;
    }
}

extern "C" void kernel_launch(void* const* d_in, const int* in_sizes, int n_in,
                              void* d_out, int out_size, void* d_ws, size_t ws_size,
                              hipStream_t stream) {
    const float* x   = (const float*)d_in[0];
    const int*   ei  = (const int*)d_in[1];   // [2, E]: src = ei[e], dst = ei[E+e]
    const float* W   = (const float*)d_in[2];
    const float* b   = (const float*)d_in[3];
    float*       out = (float*)d_out;

    const int N = in_sizes[0] / C;
    const int E = in_sizes[1] / 2;
    const int* src = ei;
    const int* dst = ei + E;

    // workspace layout (256B aligned slots)
    char* ws = (char*)d_ws;
    size_t o = 0;
    auto carve = [&](size_t bytes) { char* p = ws + o; o = (o + bytes + 255) & ~(size_t)255; return p; };
    unsigned* deg    = (unsigned*)carve((size_t)N * 4);
    unsigned* offs   = (unsigned*)carve((size_t)N * 4);
    unsigned* bsum   = (unsigned*)carve(1024 * 4);
    float*    dis    = (float*)carve((size_t)N * 4);
    unsigned* rank   = (unsigned*)carve((size_t)E * 4);
    unsigned* ssrc   = (unsigned*)carve((size_t)E * 4);
    float*    hs     = (float*)carve((size_t)N * C * 4);

    // zero degree counters only
    hipMemsetAsync(deg, 0, (size_t)N * 4, stream);

    // degree histogram + per-edge rank
    count_deg_kernel<<<(E + 255) / 256, 256, 0, stream>>>(dst, deg, rank, E);

    // exclusive prefix sum of deg -> offs (+ fused dis)
    int nb = (N + 1023) / 1024;
    scan1_kernel<<<nb, 256, 0, stream>>>(deg, offs, bsum, dis, N);
    scan2_kernel<<<1, 256, 0, stream>>>(bsum, nb);

    // counting-sort edges by dst (atomic-free)
    bucket_kernel<<<(E + 255) / 256, 256, 0, stream>>>(src, dst, offs, bsum, rank, ssrc, E);

    // hs = dis * (x @ W)
    gemm64_kernel<<<(N + 63) / 64, 256, 0, stream>>>(x, W, dis, hs, N);

    // gather + self loop + bias
    gather_kernel<<<(N + 3) / 4, 256, 0, stream>>>(offs, bsum, deg, ssrc, dis, hs, b, out, N);
}

// Round 6
// 152.180 us; speedup vs baseline: 2.0020x; 1.9962x over previous
//
#include <hip/hip_runtime.h>
#include <hip/hip_bf16.h>

#define C 64

// ---- count in-degree over dst; atomic return = rank of edge within its bucket ----
__global__ void count_deg_kernel(const int* __restrict__ dst, unsigned* __restrict__ deg,
                                 unsigned* __restrict__ rank, int E) {
    int e = blockIdx.x * blockDim.x + threadIdx.x;
    if (e < E) {
        rank[e] = atomicAdd(&deg[dst[e]], 1u);
    }
}

// ---- exclusive scan level 1 (1024/block) + dis = rsqrt(deg+1) fused ----
__global__ void scan1_kernel(const unsigned* __restrict__ deg, unsigned* __restrict__ offs,
                             unsigned* __restrict__ bsum, float* __restrict__ dis, int n) {
    __shared__ unsigned s[256];
    int t = threadIdx.x;
    int base = blockIdx.x * 1024 + t * 4;
    unsigned v0 = 0, v1 = 0, v2 = 0, v3 = 0;
    if (base + 0 < n) v0 = deg[base + 0];
    if (base + 1 < n) v1 = deg[base + 1];
    if (base + 2 < n) v2 = deg[base + 2];
    if (base + 3 < n) v3 = deg[base + 3];
    if (base + 0 < n) dis[base + 0] = rsqrtf((float)(v0 + 1u));
    if (base + 1 < n) dis[base + 1] = rsqrtf((float)(v1 + 1u));
    if (base + 2 < n) dis[base + 2] = rsqrtf((float)(v2 + 1u));
    if (base + 3 < n) dis[base + 3] = rsqrtf((float)(v3 + 1u));
    s[t] = v0 + v1 + v2 + v3;
    __syncthreads();
    for (int d = 1; d < 256; d <<= 1) {
        unsigned val = (t >= d) ? s[t - d] : 0u;
        __syncthreads();
        s[t] += val;
        __syncthreads();
    }
    unsigned excl = (t == 0) ? 0u : s[t - 1];
    if (t == 255) bsum[blockIdx.x] = s[255];
    if (base + 0 < n) offs[base + 0] = excl;
    if (base + 1 < n) offs[base + 1] = excl + v0;
    if (base + 2 < n) offs[base + 2] = excl + v0 + v1;
    if (base + 3 < n) offs[base + 3] = excl + v0 + v1 + v2;
}

// ---- scan block sums (single block; nb <= 256) ----
__global__ void scan2_kernel(unsigned* __restrict__ bsum, int nb) {
    __shared__ unsigned s[256];
    int t = threadIdx.x;
    s[t] = (t < nb) ? bsum[t] : 0u;
    __syncthreads();
    for (int d = 1; d < 256; d <<= 1) {
        unsigned val = (t >= d) ? s[t - d] : 0u;
        __syncthreads();
        s[t] += val;
        __syncthreads();
    }
    if (t < nb) bsum[t] = (t == 0) ? 0u : s[t - 1];
}

// ---- bucket edges by dst using precomputed rank (no atomics) ----
__global__ void bucket_kernel(const int* __restrict__ src, const int* __restrict__ dst,
                              const unsigned* __restrict__ offs, const unsigned* __restrict__ bsum,
                              const unsigned* __restrict__ rank, unsigned* __restrict__ ssrc, int E) {
    int e = blockIdx.x * blockDim.x + threadIdx.x;
    if (e < E) {
        int d = dst[e];
        unsigned pos = offs[d] + bsum[d >> 10] + rank[e];
        ssrc[pos] = (unsigned)src[e];
    }
}

// ---- hs = dis[row] * (x @ W) ----
// K split into 4 quarters: per thread only 16 W floats resident (spill-proof at
// any VGPR cap; round 4/5's wcol[64] spilled to scratch: 292MB fetch, 200us).
// 16 per-row accumulators live across quarters; x rows are wave-uniform ->
// s_load broadcasts on the scalar pipe.
__global__ void gemm64_kernel(const float* __restrict__ x, const float* __restrict__ W,
                              const float* __restrict__ dis, float* __restrict__ hs, int n) {
    __shared__ float Wl[64 * 64];
    int tid = threadIdx.x;
    for (int i = tid; i < 1024; i += 256) {
        ((float4*)Wl)[i] = ((const float4*)W)[i];
    }
    __syncthreads();
    int c = tid & 63;
    // wave-uniform row base so x-row loads become scalar broadcasts
    int wv = __builtin_amdgcn_readfirstlane((int)(threadIdx.x >> 6));
    int rbase = blockIdx.x * 64 + wv * 16;
    if (rbase >= n) return;               // wave-uniform
    bool full = (rbase + 16 <= n);        // wave-uniform

    float acc[16];
    #pragma unroll
    for (int j = 0; j < 16; ++j) acc[j] = 0.0f;

    #pragma unroll
    for (int kq = 0; kq < 4; ++kq) {
        // this k-quarter's W column segment -> 16 VGPRs (conflict-free LDS reads)
        float wreg[16];
        #pragma unroll
        for (int kk = 0; kk < 16; ++kk) {
            wreg[kk] = Wl[(kq * 16 + kk) * 64 + c];
        }
        if (full) {
            #pragma unroll
            for (int j = 0; j < 16; ++j) {
                const float* xr = x + (size_t)(rbase + j) * C + kq * 16;
                #pragma unroll
                for (int kk = 0; kk < 16; ++kk) {
                    acc[j] = fmaf(xr[kk], wreg[kk], acc[j]);
                }
            }
        } else {
            #pragma unroll
            for (int j = 0; j < 16; ++j) {
                if (rbase + j < n) {      // wave-uniform
                    const float* xr = x + (size_t)(rbase + j) * C + kq * 16;
                    #pragma unroll
                    for (int kk = 0; kk < 16; ++kk) {
                        acc[j] = fmaf(xr[kk], wreg[kk], acc[j]);
                    }
                }
            }
        }
    }
    if (full) {
        #pragma unroll
        for (int j = 0; j < 16; ++j) {
            hs[(size_t)(rbase + j) * C + c] = acc[j] * dis[rbase + j];
        }
    } else {
        #pragma unroll
        for (int j = 0; j < 16; ++j) {
            if (rbase + j < n) {
                hs[(size_t)(rbase + j) * C + c] = acc[j] * dis[rbase + j];
            }
        }
    }
}

// ---- gather: one wave per node; 8 edges in flight (16 lanes x float4 each) ----
__global__ void gather_kernel(const unsigned* __restrict__ offs, const unsigned* __restrict__ bsum,
                              const unsigned* __restrict__ deg, const unsigned* __restrict__ ssrc,
                              const float* __restrict__ dis, const float* __restrict__ hs,
                              const float* __restrict__ b, float* __restrict__ out, int n) {
    int node = blockIdx.x * 4 + (threadIdx.x >> 6);
    if (node >= n) return;
    int lane = threadIdx.x & 63;
    int g = lane >> 4;          // edge group 0..3
    int l = lane & 15;          // float4 slot within row
    unsigned off = offs[node] + bsum[node >> 10];
    unsigned dg  = deg[node];
    float4 acc = {0.f, 0.f, 0.f, 0.f};
    unsigned k = 0;
    for (; k + 8 <= dg; k += 8) {
        unsigned s0 = ssrc[off + k + g];
        unsigned s1 = ssrc[off + k + 4 + g];
        float4 v0 = ((const float4*)(hs + (size_t)s0 * C))[l];
        float4 v1 = ((const float4*)(hs + (size_t)s1 * C))[l];
        acc.x += v0.x + v1.x; acc.y += v0.y + v1.y;
        acc.z += v0.z + v1.z; acc.w += v0.w + v1.w;
    }
    if (k + 4 <= dg) {
        unsigned s0 = ssrc[off + k + g];
        float4 v0 = ((const float4*)(hs + (size_t)s0 * C))[l];
        acc.x += v0.x; acc.y += v0.y; acc.z += v0.z; acc.w += v0.w;
        k += 4;
    }
    if (k + g < dg) {
        unsigned s0 = ssrc[off + k + g];
        float4 v0 = ((const float4*)(hs + (size_t)s0 * C))[l];
        acc.x += v0.x; acc.y += v0.y; acc.z += v0.z; acc.w += v0.w;
    }
    acc.x += __shfl_xor(acc.x, 16); acc.y += __shfl_xor(acc.y, 16);
    acc.z += __shfl_xor(acc.z, 16); acc.w += __shfl_xor(acc.w, 16);
    acc.x += __shfl_xor(acc.x, 32); acc.y += __shfl_xor(acc.y, 32);
    acc.z += __shfl_xor(acc.z, 32); acc.w += __shfl_xor(acc.w, 32);
    if (g == 0) {
        float di = dis[node];
        float4 hv = ((const float4*)(hs + (size_t)node * C))[l];
        float4 bv = ((const float4*)b)[l];
        float4 o;
        o.x = di * (hv.x + acc.x) + bv.x;
        o.y = di * (hv.y + acc.y) + bv.y;
        o.z = di * (hv.z + acc.z) + bv.z;
        o.w = di * (hv.w + acc.w) + bv.w;
        ((float4*)(out + (size_t)node * C))[l] = o;
    }
}

extern "C" void kernel_launch(void* const* d_in, const int* in_sizes, int n_in,
                              void* d_out, int out_size, void* d_ws, size_t ws_size,
                              hipStream_t stream) {
    const float* x   = (const float*)d_in[0];
    const int*   ei  = (const int*)d_in[1];   // [2, E]: src = ei[e], dst = ei[E+e]
    const float* W   = (const float*)d_in[2];
    const float* b   = (const float*)d_in[3];
    float*       out = (float*)d_out;

    const int N = in_sizes[0] / C;
    const int E = in_sizes[1] / 2;
    const int* src = ei;
    const int* dst = ei + E;

    // workspace layout (256B aligned slots)
    char* ws = (char*)d_ws;
    size_t o = 0;
    auto carve = [&](size_t bytes) { char* p = ws + o; o = (o + bytes + 255) & ~(size_t)255; return p; };
    unsigned* deg    = (unsigned*)carve((size_t)N * 4);
    unsigned* offs   = (unsigned*)carve((size_t)N * 4);
    unsigned* bsum   = (unsigned*)carve(1024 * 4);
    float*    dis    = (float*)carve((size_t)N * 4);
    unsigned* rank   = (unsigned*)carve((size_t)E * 4);
    unsigned* ssrc   = (unsigned*)carve((size_t)E * 4);
    float*    hs     = (float*)carve((size_t)N * C * 4);

    // zero degree counters only
    hipMemsetAsync(deg, 0, (size_t)N * 4, stream);

    // degree histogram + per-edge rank
    count_deg_kernel<<<(E + 255) / 256, 256, 0, stream>>>(dst, deg, rank, E);

    // exclusive prefix sum of deg -> offs (+ fused dis)
    int nb = (N + 1023) / 1024;
    scan1_kernel<<<nb, 256, 0, stream>>>(deg, offs, bsum, dis, N);
    scan2_kernel<<<1, 256, 0, stream>>>(bsum, nb);

    // counting-sort edges by dst (atomic-free)
    bucket_kernel<<<(E + 255) / 256, 256, 0, stream>>>(src, dst, offs, bsum, rank, ssrc, E);

    // hs = dis * (x @ W)
    gemm64_kernel<<<(N + 63) / 64, 256, 0, stream>>>(x, W, dis, hs, N);

    // gather + self loop + bias
    gather_kernel<<<(N + 3) / 4, 256, 0, stream>>>(offs, bsum, deg, ssrc, dis, hs, b, out, N);
}

// Round 7
// 138.042 us; speedup vs baseline: 2.2071x; 1.1024x over previous
//
#include <hip/hip_runtime.h>
#include <hip/hip_bf16.h>

#define C 64

// ---- count in-degree over dst; atomic return = rank of edge within its bucket ----
__global__ void count_deg_kernel(const int* __restrict__ dst, unsigned* __restrict__ deg,
                                 unsigned* __restrict__ rank, int E) {
    int e = blockIdx.x * blockDim.x + threadIdx.x;
    if (e < E) {
        rank[e] = atomicAdd(&deg[dst[e]], 1u);
    }
}

// ---- exclusive scan level 1 (1024/block) + dis = rsqrt(deg+1) fused ----
__global__ void scan1_kernel(const unsigned* __restrict__ deg, unsigned* __restrict__ offs,
                             unsigned* __restrict__ bsum, float* __restrict__ dis, int n) {
    __shared__ unsigned s[256];
    int t = threadIdx.x;
    int base = blockIdx.x * 1024 + t * 4;
    unsigned v0 = 0, v1 = 0, v2 = 0, v3 = 0;
    if (base + 0 < n) v0 = deg[base + 0];
    if (base + 1 < n) v1 = deg[base + 1];
    if (base + 2 < n) v2 = deg[base + 2];
    if (base + 3 < n) v3 = deg[base + 3];
    if (base + 0 < n) dis[base + 0] = rsqrtf((float)(v0 + 1u));
    if (base + 1 < n) dis[base + 1] = rsqrtf((float)(v1 + 1u));
    if (base + 2 < n) dis[base + 2] = rsqrtf((float)(v2 + 1u));
    if (base + 3 < n) dis[base + 3] = rsqrtf((float)(v3 + 1u));
    s[t] = v0 + v1 + v2 + v3;
    __syncthreads();
    for (int d = 1; d < 256; d <<= 1) {
        unsigned val = (t >= d) ? s[t - d] : 0u;
        __syncthreads();
        s[t] += val;
        __syncthreads();
    }
    unsigned excl = (t == 0) ? 0u : s[t - 1];
    if (t == 255) bsum[blockIdx.x] = s[255];
    if (base + 0 < n) offs[base + 0] = excl;
    if (base + 1 < n) offs[base + 1] = excl + v0;
    if (base + 2 < n) offs[base + 2] = excl + v0 + v1;
    if (base + 3 < n) offs[base + 3] = excl + v0 + v1 + v2;
}

// ---- scan block sums (single block; nb <= 256) ----
__global__ void scan2_kernel(unsigned* __restrict__ bsum, int nb) {
    __shared__ unsigned s[256];
    int t = threadIdx.x;
    s[t] = (t < nb) ? bsum[t] : 0u;
    __syncthreads();
    for (int d = 1; d < 256; d <<= 1) {
        unsigned val = (t >= d) ? s[t - d] : 0u;
        __syncthreads();
        s[t] += val;
        __syncthreads();
    }
    if (t < nb) bsum[t] = (t == 0) ? 0u : s[t - 1];
}

// ---- bucket edges by dst using precomputed rank (no atomics) ----
__global__ void bucket_kernel(const int* __restrict__ src, const int* __restrict__ dst,
                              const unsigned* __restrict__ offs, const unsigned* __restrict__ bsum,
                              const unsigned* __restrict__ rank, unsigned* __restrict__ ssrc, int E) {
    int e = blockIdx.x * blockDim.x + threadIdx.x;
    if (e < E) {
        int d = dst[e];
        unsigned pos = offs[d] + bsum[d >> 10] + rank[e];
        ssrc[pos] = (unsigned)src[e];
    }
}

// ---- hs = dis[row] * (x @ W): LDS-tiled, 4x4 register micro-tile ----
// Round-6 scalar-broadcast version was SMEM-latency-bound (s_load streaming
// through K$: 55us, VALUBusy 13%). Here x goes through the vector path: 64x64
// x-tile staged in LDS (stride 68 pad -> 2-way-or-less bank aliasing on b128
// row reads), each thread computes 4 rows x 4 channels (16 acc, no spill).
__global__ void __launch_bounds__(256)
gemm64_kernel(const float* __restrict__ x, const float* __restrict__ W,
              const float* __restrict__ dis, float* __restrict__ hs, int n) {
    __shared__ float Xl[64][68];
    __shared__ float Wl[64][64];
    int tid = threadIdx.x;
    int rbase = blockIdx.x * 64;
    // stage W (flat 4096 floats, layout identical)
    for (int i = tid; i < 1024; i += 256) {
        ((float4*)Wl)[i] = ((const float4*)W)[i];
    }
    // stage x tile: 64 rows x 16 float4 slots
    for (int i = tid; i < 1024; i += 256) {
        int r = i >> 4, kq = i & 15;
        float4 v;
        if (rbase + r < n) v = ((const float4*)(x + (size_t)(rbase + r) * C))[kq];
        else               v = make_float4(0.f, 0.f, 0.f, 0.f);
        *(float4*)&Xl[r][kq * 4] = v;
    }
    __syncthreads();

    int tx = tid & 15;      // channel group: channels 4tx..4tx+3
    int ty = tid >> 4;      // row group: rows 4ty..4ty+3
    float4 acc[4];
    #pragma unroll
    for (int j = 0; j < 4; ++j) acc[j] = make_float4(0.f, 0.f, 0.f, 0.f);

    for (int kb = 0; kb < 16; ++kb) {
        float4 wv0 = *(const float4*)&Wl[kb * 4 + 0][tx * 4];
        float4 wv1 = *(const float4*)&Wl[kb * 4 + 1][tx * 4];
        float4 wv2 = *(const float4*)&Wl[kb * 4 + 2][tx * 4];
        float4 wv3 = *(const float4*)&Wl[kb * 4 + 3][tx * 4];
        #pragma unroll
        for (int j = 0; j < 4; ++j) {
            float4 xv = *(const float4*)&Xl[ty * 4 + j][kb * 4];
            acc[j].x = fmaf(xv.x, wv0.x, acc[j].x);
            acc[j].y = fmaf(xv.x, wv0.y, acc[j].y);
            acc[j].z = fmaf(xv.x, wv0.z, acc[j].z);
            acc[j].w = fmaf(xv.x, wv0.w, acc[j].w);
            acc[j].x = fmaf(xv.y, wv1.x, acc[j].x);
            acc[j].y = fmaf(xv.y, wv1.y, acc[j].y);
            acc[j].z = fmaf(xv.y, wv1.z, acc[j].z);
            acc[j].w = fmaf(xv.y, wv1.w, acc[j].w);
            acc[j].x = fmaf(xv.z, wv2.x, acc[j].x);
            acc[j].y = fmaf(xv.z, wv2.y, acc[j].y);
            acc[j].z = fmaf(xv.z, wv2.z, acc[j].z);
            acc[j].w = fmaf(xv.z, wv2.w, acc[j].w);
            acc[j].x = fmaf(xv.w, wv3.x, acc[j].x);
            acc[j].y = fmaf(xv.w, wv3.y, acc[j].y);
            acc[j].z = fmaf(xv.w, wv3.z, acc[j].z);
            acc[j].w = fmaf(xv.w, wv3.w, acc[j].w);
        }
    }
    #pragma unroll
    for (int j = 0; j < 4; ++j) {
        int row = rbase + ty * 4 + j;
        if (row < n) {
            float d = dis[row];
            float4 o = make_float4(acc[j].x * d, acc[j].y * d, acc[j].z * d, acc[j].w * d);
            ((float4*)(hs + (size_t)row * C))[tx] = o;
        }
    }
}

// ---- gather: one wave per node; 8 edges in flight (16 lanes x float4 each) ----
__global__ void gather_kernel(const unsigned* __restrict__ offs, const unsigned* __restrict__ bsum,
                              const unsigned* __restrict__ deg, const unsigned* __restrict__ ssrc,
                              const float* __restrict__ dis, const float* __restrict__ hs,
                              const float* __restrict__ b, float* __restrict__ out, int n) {
    int node = blockIdx.x * 4 + (threadIdx.x >> 6);
    if (node >= n) return;
    int lane = threadIdx.x & 63;
    int g = lane >> 4;          // edge group 0..3
    int l = lane & 15;          // float4 slot within row
    unsigned off = offs[node] + bsum[node >> 10];
    unsigned dg  = deg[node];
    float4 acc = {0.f, 0.f, 0.f, 0.f};
    unsigned k = 0;
    for (; k + 8 <= dg; k += 8) {
        unsigned s0 = ssrc[off + k + g];
        unsigned s1 = ssrc[off + k + 4 + g];
        float4 v0 = ((const float4*)(hs + (size_t)s0 * C))[l];
        float4 v1 = ((const float4*)(hs + (size_t)s1 * C))[l];
        acc.x += v0.x + v1.x; acc.y += v0.y + v1.y;
        acc.z += v0.z + v1.z; acc.w += v0.w + v1.w;
    }
    if (k + 4 <= dg) {
        unsigned s0 = ssrc[off + k + g];
        float4 v0 = ((const float4*)(hs + (size_t)s0 * C))[l];
        acc.x += v0.x; acc.y += v0.y; acc.z += v0.z; acc.w += v0.w;
        k += 4;
    }
    if (k + g < dg) {
        unsigned s0 = ssrc[off + k + g];
        float4 v0 = ((const float4*)(hs + (size_t)s0 * C))[l];
        acc.x += v0.x; acc.y += v0.y; acc.z += v0.z; acc.w += v0.w;
    }
    acc.x += __shfl_xor(acc.x, 16); acc.y += __shfl_xor(acc.y, 16);
    acc.z += __shfl_xor(acc.z, 16); acc.w += __shfl_xor(acc.w, 16);
    acc.x += __shfl_xor(acc.x, 32); acc.y += __shfl_xor(acc.y, 32);
    acc.z += __shfl_xor(acc.z, 32); acc.w += __shfl_xor(acc.w, 32);
    if (g == 0) {
        float di = dis[node];
        float4 hv = ((const float4*)(hs + (size_t)node * C))[l];
        float4 bv = ((const float4*)b)[l];
        float4 o;
        o.x = di * (hv.x + acc.x) + bv.x;
        o.y = di * (hv.y + acc.y) + bv.y;
        o.z = di * (hv.z + acc.z) + bv.z;
        o.w = di * (hv.w + acc.w) + bv.w;
        ((float4*)(out + (size_t)node * C))[l] = o;
    }
}

extern "C" void kernel_launch(void* const* d_in, const int* in_sizes, int n_in,
                              void* d_out, int out_size, void* d_ws, size_t ws_size,
                              hipStream_t stream) {
    const float* x   = (const float*)d_in[0];
    const int*   ei  = (const int*)d_in[1];   // [2, E]: src = ei[e], dst = ei[E+e]
    const float* W   = (const float*)d_in[2];
    const float* b   = (const float*)d_in[3];
    float*       out = (float*)d_out;

    const int N = in_sizes[0] / C;
    const int E = in_sizes[1] / 2;
    const int* src = ei;
    const int* dst = ei + E;

    // workspace layout (256B aligned slots)
    char* ws = (char*)d_ws;
    size_t o = 0;
    auto carve = [&](size_t bytes) { char* p = ws + o; o = (o + bytes + 255) & ~(size_t)255; return p; };
    unsigned* deg    = (unsigned*)carve((size_t)N * 4);
    unsigned* offs   = (unsigned*)carve((size_t)N * 4);
    unsigned* bsum   = (unsigned*)carve(1024 * 4);
    float*    dis    = (float*)carve((size_t)N * 4);
    unsigned* rank   = (unsigned*)carve((size_t)E * 4);
    unsigned* ssrc   = (unsigned*)carve((size_t)E * 4);
    float*    hs     = (float*)carve((size_t)N * C * 4);

    // zero degree counters only
    hipMemsetAsync(deg, 0, (size_t)N * 4, stream);

    // degree histogram + per-edge rank
    count_deg_kernel<<<(E + 255) / 256, 256, 0, stream>>>(dst, deg, rank, E);

    // exclusive prefix sum of deg -> offs (+ fused dis)
    int nb = (N + 1023) / 1024;
    scan1_kernel<<<nb, 256, 0, stream>>>(deg, offs, bsum, dis, N);
    scan2_kernel<<<1, 256, 0, stream>>>(bsum, nb);

    // counting-sort edges by dst (atomic-free)
    bucket_kernel<<<(E + 255) / 256, 256, 0, stream>>>(src, dst, offs, bsum, rank, ssrc, E);

    // hs = dis * (x @ W)
    gemm64_kernel<<<(N + 63) / 64, 256, 0, stream>>>(x, W, dis, hs, N);

    // gather + self loop + bias
    gather_kernel<<<(N + 3) / 4, 256, 0, stream>>>(offs, bsum, deg, ssrc, dis, hs, b, out, N);
}